// Round 7
// baseline (483.957 us; speedup 1.0000x reference)
//
#include <hip/hip_runtime.h>
#include <hip/hip_bf16.h>

// GNN: h = x@We^T + be; 2x { h = relu(segsum(h[col],row) @ W^T + b) };
// out = relu(mean(h,1) @ Wc1^T + bc1) @ Wc2^T + bc2   (scalar fp32)
//
// Restructure: relu((A h) W^T + b) == relu(A (h W^T) + b)  (A = sparse adj).
// R7: gemm_mx unchanged from R6 (MX fp8 16x16x128, unit scales, granule-split
// LDS, 1578 TF). Dispatch-count cut 17 -> 11: single segmented fp32->fp8 cvt,
// aggr+row_mean fused (h2 64MB round-trip eliminated, atomic partial means),
// clf1+clf2 fused via atomics, zero-init kernels merged.

#define N_NODES 4096
#define IN_DIM_ 512
#define HID_ 4096
#define NEDGE 65536

typedef float f32x4 __attribute__((ext_vector_type(4)));
typedef float f32x2 __attribute__((ext_vector_type(2)));
typedef int i32x8 __attribute__((ext_vector_type(8)));

#define ACT_SCALE 8.0f     // activations fp8 = 8 x true
#define W_SCALE 256.0f     // weights fp8 = 256 x true
#define G_SCALE 8.0f       // g fp8 = 8 x true
// gemm acc = 2048 x true; fp8-store multiplier = 8/2048
#define G_STORE_MUL (8.0f / 2048.0f)

__device__ __forceinline__ unsigned char f2fp8(float f) {
  int w = __builtin_amdgcn_cvt_pk_fp8_f32(f, f, 0, false);  // OCP e4m3
  return (unsigned char)(w & 0xff);
}
// decode 4 fp8 bytes of w into acc[0..3] (+=)
__device__ __forceinline__ void fp8x4_acc(int w, float* acc) {
  f32x2 lo = __builtin_amdgcn_cvt_pk_f32_fp8(w, false);
  f32x2 hi = __builtin_amdgcn_cvt_pk_f32_fp8(w, true);
  acc[0] += lo[0]; acc[1] += lo[1]; acc[2] += hi[0]; acc[3] += hi[1];
}

// ---- zero counts/cursor/hm (contiguous 12288 i32) + out scalar ----
__global__ __launch_bounds__(256) void zero_misc(int* __restrict__ p, int n,
                                                 float* __restrict__ out) {
  int i = blockIdx.x * 256 + threadIdx.x;
  if (i < n) p[i] = 0;
  if (i == 0) out[0] = 0.0f;
}

// ---- segmented fp32 -> fp8 (x scale), 8 elems/thread ----
// blocks: [0,1024) x | [1024,2048) We | [2048,10240) W1 | [10240,18432) W2
__global__ __launch_bounds__(256) void cvt_all(
    const float* __restrict__ x, const float* __restrict__ we,
    const float* __restrict__ w1, const float* __restrict__ w2,
    unsigned char* __restrict__ xo, unsigned char* __restrict__ weo,
    unsigned char* __restrict__ w1o, unsigned char* __restrict__ w2o) {
  const int b = blockIdx.x;
  const float* in; unsigned char* out; float scale; int base;
  if (b < 1024)       { in = x;  out = xo;  scale = ACT_SCALE; base = b; }
  else if (b < 2048)  { in = we; out = weo; scale = W_SCALE;   base = b - 1024; }
  else if (b < 10240) { in = w1; out = w1o; scale = W_SCALE;   base = b - 2048; }
  else                { in = w2; out = w2o; scale = W_SCALE;   base = b - 10240; }
  const int i = (base * 256 + threadIdx.x) * 8;
  const float4 a = *(const float4*)(in + i);
  const float4 c = *(const float4*)(in + i + 4);
  int w0 = __builtin_amdgcn_cvt_pk_fp8_f32(a.x * scale, a.y * scale, 0, false);
  w0 = __builtin_amdgcn_cvt_pk_fp8_f32(a.z * scale, a.w * scale, w0, true);
  int w1v = __builtin_amdgcn_cvt_pk_fp8_f32(c.x * scale, c.y * scale, 0, false);
  w1v = __builtin_amdgcn_cvt_pk_fp8_f32(c.z * scale, c.w * scale, w1v, true);
  *(int2*)(out + i) = make_int2(w0, w1v);
}

// ---------------- CSR build ----------------
__global__ __launch_bounds__(256) void hist_rows(const int* __restrict__ row,
                                                 int* __restrict__ counts) {
  int e = blockIdx.x * 256 + threadIdx.x;
  if (e < NEDGE) atomicAdd(&counts[row[e]], 1);
}

// exclusive scan of counts[4096] -> starts[4097]; single block of 1024 threads
__global__ __launch_bounds__(1024) void scan4096(const int* __restrict__ counts,
                                                 int* __restrict__ starts) {
  __shared__ int sa[1024], sb[1024];
  const int t = threadIdx.x;
  const int c0 = counts[t * 4], c1 = counts[t * 4 + 1],
            c2 = counts[t * 4 + 2], c3 = counts[t * 4 + 3];
  const int local = c0 + c1 + c2 + c3;
  sa[t] = local;
  __syncthreads();
  int* src = sa; int* dst = sb;
  for (int off = 1; off < 1024; off <<= 1) {
    int v = src[t];
    if (t >= off) v += src[t - off];
    dst[t] = v;
    __syncthreads();
    int* tmp = src; src = dst; dst = tmp;
  }
  const int excl = (t == 0) ? 0 : src[t - 1];
  starts[t * 4]     = excl;
  starts[t * 4 + 1] = excl + c0;
  starts[t * 4 + 2] = excl + c0 + c1;
  starts[t * 4 + 3] = excl + c0 + c1 + c2;
  if (t == 1023) starts[4096] = excl + local;
}

__global__ __launch_bounds__(256) void fill_adj(const int* __restrict__ row,
                                                const int* __restrict__ col,
                                                const int* __restrict__ starts,
                                                int* __restrict__ cursor,
                                                int* __restrict__ adj) {
  int e = blockIdx.x * 256 + threadIdx.x;
  if (e >= NEDGE) return;
  int r = row[e];
  int p = atomicAdd(&cursor[r], 1);
  adj[starts[r] + p] = col[e];
}

// ---- MX fp8 GEMM: C_fp8 = fp8(mul*(A@B^T) [+ ACT_SCALE*bias]) ----
// 128x128 tile, BK=128, 4 waves each 64x64 (4x4 of 16x16x128 MX MFMA,
// unit scales). LDS: granule-split blocks, 16 KB/operand. (R6-validated.)
__device__ __forceinline__ i32x8 ld_frag(const char* base0) {
  const int4 lo = *(const int4*)(base0);          // orig k quad*32 .. +16
  const int4 hi = *(const int4*)(base0 + 8192);   // orig k quad*32+16 .. +32
  i32x8 f;
  f[0] = lo.x; f[1] = lo.y; f[2] = lo.z; f[3] = lo.w;
  f[4] = hi.x; f[5] = hi.y; f[6] = hi.z; f[7] = hi.w;
  return f;
}

__global__ __launch_bounds__(256) void gemm_mx(
    const unsigned char* __restrict__ A, const unsigned char* __restrict__ B,
    unsigned char* __restrict__ C, int N, int K,
    const float* __restrict__ bias, float mul) {
  __shared__ unsigned char As[128 * 128];  // [As0: 128 rows x 64B][As1: same]
  __shared__ unsigned char Bs[128 * 128];
  const int t = threadIdx.x;
  const int bm = blockIdx.x * 128, bn = blockIdx.y * 128;
  const int wave = t >> 6, lane = t & 63;
  const int wm = (wave >> 1) * 64, wn = (wave & 1) * 64;
  const int m16 = lane & 15, quad = lane >> 4;

  f32x4 acc[4][4] = {};

  // staging: thread t -> row t>>2 (0..63), granule q = t&3.
  // As0 pos (row,q) holds orig granule 2q (byte q*32); As1 holds 2q+1 (+16).
  const int srow = t >> 2;
  const int sg = (t & 3) * 32;
  const unsigned char* Ag0 = A + (size_t)(bm + srow) * K + sg;
  const unsigned char* Ag1 = A + (size_t)(bm + 64 + srow) * K + sg;
  const unsigned char* Bg0 = B + (size_t)(bn + srow) * K + sg;
  const unsigned char* Bg1 = B + (size_t)(bn + 64 + srow) * K + sg;
  char* AsB = (char*)As;
  char* BsB = (char*)Bs;

#define GLDS(gp, lp)                                                       \
  __builtin_amdgcn_global_load_lds(                                        \
      (const __attribute__((address_space(1))) void*)(gp),                 \
      (__attribute__((address_space(3))) void*)(lp), 16, 0, 0)

  for (int kb = 0; kb < K; kb += 128) {
    GLDS(Ag0 + kb,      AsB + t * 16);           // As0 rows 0..63
    GLDS(Ag1 + kb,      AsB + 4096 + t * 16);    // As0 rows 64..127
    GLDS(Ag0 + kb + 16, AsB + 8192 + t * 16);    // As1 rows 0..63
    GLDS(Ag1 + kb + 16, AsB + 12288 + t * 16);   // As1 rows 64..127
    GLDS(Bg0 + kb,      BsB + t * 16);
    GLDS(Bg1 + kb,      BsB + 4096 + t * 16);
    GLDS(Bg0 + kb + 16, BsB + 8192 + t * 16);
    GLDS(Bg1 + kb + 16, BsB + 12288 + t * 16);
    __syncthreads();

    // fragment: lane holds A[m = lane&15][k = quad*32 + j], j=0..31
    i32x8 af[4], bfr[4];
#pragma unroll
    for (int r = 0; r < 4; ++r)
      af[r] = ld_frag(AsB + (wm + r * 16 + m16) * 64 + quad * 16);
#pragma unroll
    for (int c = 0; c < 4; ++c)
      bfr[c] = ld_frag(BsB + (wn + c * 16 + m16) * 64 + quad * 16);
#pragma unroll
    for (int r = 0; r < 4; ++r)
#pragma unroll
      for (int c = 0; c < 4; ++c)
        acc[r][c] = __builtin_amdgcn_mfma_scale_f32_16x16x128_f8f6f4(
            af[r], bfr[c], acc[r][c], 0, 0,      // cbsz=0 (fp8), blgp=0 (fp8)
            0, 0x7f7f7f7f, 0, 0x7f7f7f7f);       // unit E8M0 scales
    __syncthreads();
  }
#undef GLDS

  // C/D layout (16x16 family, shape-determined): col=lane&15, row=quad*4+reg
#pragma unroll
  for (int r = 0; r < 4; ++r) {
#pragma unroll
    for (int c = 0; c < 4; ++c) {
      const int row0 = bm + wm + r * 16 + quad * 4;
      const int col = bn + wn + c * 16 + m16;
      const float bv = bias ? ACT_SCALE * bias[col] : 0.0f;
#pragma unroll
      for (int i = 0; i < 4; ++i) {
        C[(size_t)(row0 + i) * N + col] = f2fp8(acc[r][c][i] * mul + bv);
      }
    }
  }
}

// ---- aggregation (fp8 g in): h = relu(sum g[c]/G_SCALE + b) -> fp8 x ACT ----
__global__ __launch_bounds__(256) void aggr_f8out(
    const unsigned char* __restrict__ g, const int* __restrict__ starts,
    const int* __restrict__ adj, const float* __restrict__ bias,
    unsigned char* __restrict__ hout) {
  const int node = blockIdx.y;
  const int f0 = blockIdx.x * 2048 + threadIdx.x * 8;
  float acc[8] = {0, 0, 0, 0, 0, 0, 0, 0};
  const int s = starts[node], e = starts[node + 1];
  int j = s;
  for (; j + 4 <= e; j += 4) {
    const int c0 = adj[j], c1 = adj[j + 1], c2 = adj[j + 2], c3 = adj[j + 3];
    int2 v0 = *(const int2*)(g + (size_t)c0 * HID_ + f0);
    int2 v1 = *(const int2*)(g + (size_t)c1 * HID_ + f0);
    int2 v2 = *(const int2*)(g + (size_t)c2 * HID_ + f0);
    int2 v3 = *(const int2*)(g + (size_t)c3 * HID_ + f0);
    fp8x4_acc(v0.x, acc);     fp8x4_acc(v0.y, acc + 4);
    fp8x4_acc(v1.x, acc);     fp8x4_acc(v1.y, acc + 4);
    fp8x4_acc(v2.x, acc);     fp8x4_acc(v2.y, acc + 4);
    fp8x4_acc(v3.x, acc);     fp8x4_acc(v3.y, acc + 4);
  }
  for (; j < e; ++j) {
    int2 v = *(const int2*)(g + (size_t)adj[j] * HID_ + f0);
    fp8x4_acc(v.x, acc);      fp8x4_acc(v.y, acc + 4);
  }
  const float4 b0 = *(const float4*)(bias + f0);
  const float4 b1 = *(const float4*)(bias + f0 + 4);
  const float bb[8] = {b0.x, b0.y, b0.z, b0.w, b1.x, b1.y, b1.z, b1.w};
  float v[8];
#pragma unroll
  for (int i = 0; i < 8; ++i)
    v[i] = ACT_SCALE * fmaxf(acc[i] * (1.0f / G_SCALE) + bb[i], 0.0f);
  int w0 = __builtin_amdgcn_cvt_pk_fp8_f32(v[0], v[1], 0, false);
  w0 = __builtin_amdgcn_cvt_pk_fp8_f32(v[2], v[3], w0, true);
  int w1 = __builtin_amdgcn_cvt_pk_fp8_f32(v[4], v[5], 0, false);
  w1 = __builtin_amdgcn_cvt_pk_fp8_f32(v[6], v[7], w1, true);
  *(int2*)(hout + (size_t)node * HID_ + f0) = make_int2(w0, w1);
}

// ---- final layer: hm[node] += mean contribution of relu(aggr + b2) ----
// Fuses aggr_bf16out + row_mean: h2 never materialized. hm zeroed upfront.
__global__ __launch_bounds__(256) void aggr_mean(
    const unsigned char* __restrict__ g, const int* __restrict__ starts,
    const int* __restrict__ adj, const float* __restrict__ bias,
    float* __restrict__ hm) {
  const int node = blockIdx.y;
  const int f0 = blockIdx.x * 2048 + threadIdx.x * 8;
  float acc[8] = {0, 0, 0, 0, 0, 0, 0, 0};
  const int s = starts[node], e = starts[node + 1];
  int j = s;
  for (; j + 4 <= e; j += 4) {
    const int c0 = adj[j], c1 = adj[j + 1], c2 = adj[j + 2], c3 = adj[j + 3];
    int2 v0 = *(const int2*)(g + (size_t)c0 * HID_ + f0);
    int2 v1 = *(const int2*)(g + (size_t)c1 * HID_ + f0);
    int2 v2 = *(const int2*)(g + (size_t)c2 * HID_ + f0);
    int2 v3 = *(const int2*)(g + (size_t)c3 * HID_ + f0);
    fp8x4_acc(v0.x, acc);     fp8x4_acc(v0.y, acc + 4);
    fp8x4_acc(v1.x, acc);     fp8x4_acc(v1.y, acc + 4);
    fp8x4_acc(v2.x, acc);     fp8x4_acc(v2.y, acc + 4);
    fp8x4_acc(v3.x, acc);     fp8x4_acc(v3.y, acc + 4);
  }
  for (; j < e; ++j) {
    int2 v = *(const int2*)(g + (size_t)adj[j] * HID_ + f0);
    fp8x4_acc(v.x, acc);      fp8x4_acc(v.y, acc + 4);
  }
  const float4 b0 = *(const float4*)(bias + f0);
  const float4 b1 = *(const float4*)(bias + f0 + 4);
  const float bb[8] = {b0.x, b0.y, b0.z, b0.w, b1.x, b1.y, b1.z, b1.w};
  float s8 = 0.f;
#pragma unroll
  for (int i = 0; i < 8; ++i)
    s8 += fmaxf(acc[i] * (1.0f / G_SCALE) + bb[i], 0.0f);
  // wave reduce, then block reduce, one atomic per block
  for (int off = 32; off > 0; off >>= 1) s8 += __shfl_down(s8, off);
  __shared__ float ws[4];
  const int t = threadIdx.x;
  if ((t & 63) == 0) ws[t >> 6] = s8;
  __syncthreads();
  if (t == 0)
    atomicAdd(&hm[node], (ws[0] + ws[1] + ws[2] + ws[3]) * (1.0f / (float)HID_));
}

// ---- fused classifier: out = sum_j relu(Wc1[j].hm + bc1[j]) * Wc2[j] + bc2 ----
// 512 blocks x 4 waves; wave handles one j; atomicAdd into out (zeroed upfront)
__global__ __launch_bounds__(256) void clf_fused(
    const float* __restrict__ Wc1, const float* __restrict__ bc1,
    const float* __restrict__ Wc2, const float* __restrict__ bc2,
    const float* __restrict__ hm, float* __restrict__ out) {
  const int wave = threadIdx.x >> 6, lane = threadIdx.x & 63;
  const int j = blockIdx.x * 4 + wave;
  const float* w = Wc1 + (size_t)j * HID_;
  float s = 0.f;
  for (int i = lane; i < HID_; i += 64) s += w[i] * hm[i];
  for (int off = 32; off > 0; off >>= 1) s += __shfl_down(s, off);
  if (lane == 0) {
    float z = fmaxf(s + bc1[j], 0.0f);
    float c = z * Wc2[j];
    if (j == 0) c += bc2[0];
    atomicAdd(out, c);
  }
}

extern "C" void kernel_launch(void* const* d_in, const int* in_sizes, int n_in,
                              void* d_out, int out_size, void* d_ws, size_t ws_size,
                              hipStream_t stream) {
  (void)in_sizes; (void)n_in; (void)out_size; (void)ws_size;
  const float* x       = (const float*)d_in[0];
  const int*   edge    = (const int*)d_in[1];
  const int*   row     = edge;
  const int*   col     = edge + NEDGE;
  const float* W_embed = (const float*)d_in[2];
  const float* b_embed = (const float*)d_in[3];
  const float* W1      = (const float*)d_in[4];
  const float* b1      = (const float*)d_in[5];
  const float* W2      = (const float*)d_in[6];
  const float* b2      = (const float*)d_in[7];
  const float* Wc1     = (const float*)d_in[8];
  const float* bc1     = (const float*)d_in[9];
  const float* Wc2     = (const float*)d_in[10];
  const float* bc2     = (const float*)d_in[11];
  float* out = (float*)d_out;

  char* ws = (char*)d_ws;
  size_t off = 0;
  auto alloc = [&](size_t bytes) {
    char* p = ws + off;
    off += (bytes + 255) & ~(size_t)255;
    return p;
  };
  unsigned char*  xf8  = (unsigned char*)alloc((size_t)N_NODES * IN_DIM_);
  unsigned char*  wef8 = (unsigned char*)alloc((size_t)HID_ * IN_DIM_);
  unsigned char*  w1f8 = (unsigned char*)alloc((size_t)HID_ * HID_);
  unsigned char*  w2f8 = (unsigned char*)alloc((size_t)HID_ * HID_);
  unsigned char*  h0f8 = (unsigned char*)alloc((size_t)N_NODES * HID_);
  unsigned char*  h1f8 = (unsigned char*)alloc((size_t)N_NODES * HID_);
  unsigned char*  g    = (unsigned char*)alloc((size_t)N_NODES * HID_);
  // counts, cursor, hm contiguous (zeroed by one kernel; each 16 KB,
  // alloc granularity 256 B keeps them adjacent)
  int*   counts = (int*)alloc(N_NODES * 4);
  int*   cursor = (int*)alloc(N_NODES * 4);
  float* hm     = (float*)alloc(N_NODES * 4);
  int*   starts = (int*)alloc((N_NODES + 1) * 4);
  int*   adj    = (int*)alloc(NEDGE * 4);

  // zero counts+cursor+hm (12288 i32) + out
  zero_misc<<<48, 256, 0, stream>>>(counts, 3 * N_NODES, out);
  // CSR build
  hist_rows<<<NEDGE / 256, 256, 0, stream>>>(row, counts);
  scan4096<<<1, 1024, 0, stream>>>(counts, starts);
  fill_adj<<<NEDGE / 256, 256, 0, stream>>>(row, col, starts, cursor, adj);
  // fp8 conversions (single segmented kernel)
  cvt_all<<<18432, 256, 0, stream>>>(x, W_embed, W1, W2, xf8, wef8, w1f8, w2f8);

  // embed: h0 = fp8(8 * (x @ We^T + be))
  gemm_mx<<<dim3(32, 32), 256, 0, stream>>>(xf8, wef8, h0f8, HID_, IN_DIM_,
                                            b_embed, G_STORE_MUL);
  // layer 1: g = h0 @ W1^T ; h1 = fp8(8 * relu(A g + b1))
  gemm_mx<<<dim3(32, 32), 256, 0, stream>>>(h0f8, w1f8, g, HID_, HID_,
                                            nullptr, G_STORE_MUL);
  aggr_f8out<<<dim3(2, N_NODES), 256, 0, stream>>>(g, starts, adj, b1, h1f8);
  // layer 2: g = h1 @ W2^T ; hm[node] = mean(relu(A g + b2)) directly
  gemm_mx<<<dim3(32, 32), 256, 0, stream>>>(h1f8, w2f8, g, HID_, HID_,
                                            nullptr, G_STORE_MUL);
  aggr_mean<<<dim3(2, N_NODES), 256, 0, stream>>>(g, starts, adj, b2, hm);
  // fused classifier tail
  clf_fused<<<(HID_ / 2) / 4, 256, 0, stream>>>(Wc1, bc1, Wc2, bc2, hm, out);
}